// Round 14
// baseline (274.173 us; speedup 1.0000x reference)
//
#include <hip/hip_runtime.h>

typedef _Float16 f16x8 __attribute__((ext_vector_type(8)));
typedef unsigned short ushort8 __attribute__((ext_vector_type(8)));
typedef float f32x4 __attribute__((ext_vector_type(4)));

#define C_IN     256
#define C_OUT    512
#define M_PTS    25000
#define KNN      16
#define P_BLK    4
#define ROWS     (P_BLK * KNN)   /* 64 */
#define ROWB     528             /* padded row stride in bytes (264 f16), 16B-aligned */
#define NTHREADS 256

#define MFMA16(a, b, c) __builtin_amdgcn_mfma_f32_16x16x32_f16(a, b, c, 0, 0, 0)

__device__ __forceinline__ unsigned short f2h(float f) {
    _Float16 h = (_Float16)f;
    return __builtin_bit_cast(unsigned short, h);
}

// Pack W [C_IN][C_OUT] f32 -> f16 in MFMA B-fragment order (verified):
// Wp[nt*4096 + kk*512 + lane*8 + j] = W[(kk*32 + (lane>>4)*8 + j)*C_OUT + nt*16 + (lane&15)]
__global__ void pack_w_kernel(const float* __restrict__ W, unsigned short* __restrict__ Wp) {
    int t = blockIdx.x * blockDim.x + threadIdx.x;   // 0 .. 131071
    int j    = t & 7;
    int lane = (t >> 3) & 63;
    int kk   = (t >> 9) & 7;
    int nt   = t >> 12;                               // 0..31
    int k = kk * 32 + ((lane >> 4) << 3) + j;
    int n = nt * 16 + (lane & 15);
    Wp[t] = f2h(W[k * C_OUT + n]);
}

// HAZARD LAW (R1..R13): array-held ext_vector MFMA operands in large unrolled
// regions miscompile (R6/R7/R13); bulk asm pins miscompile (R10). Named scalars
// in unrolled regions are safe (R9/R11/R12). This kernel uses ONLY named scalars.
//
// Wave->POINT mapping: each wave owns one point (16 rows = one MFMA A-operand).
// A-frags read from LDS ONCE into 8 named registers (vs R8: whole 32KB A-tile
// re-read per col-tile-pair => 512KB LDS/block). All 4 waves then sweep nt=0..31
// in near-lockstep sharing B through L1/L2 (vs R8's 4x-redundant resunk stream).
__global__ __launch_bounds__(NTHREADS, 2)
void fused_gather_ln_gemm_max(const float* __restrict__ x,
                              const int* __restrict__ idx,
                              const float* __restrict__ gamma,
                              const float* __restrict__ beta,
                              const unsigned short* __restrict__ Wp,
                              const float* __restrict__ bias,
                              float* __restrict__ out) {
    __shared__ char Ab[ROWS * ROWB];   // 33 KiB, f16 A-tile, padded rows, NO swizzle

    const int tid  = threadIdx.x;
    const int lane = tid & 63;
    const int wave = tid >> 6;
    const int m0   = blockIdx.x * P_BLK;

    // ---- Phase 1: gather + LayerNorm -> LDS (f16), VERBATIM from passing rounds ----
    float gm[16], bt[16];
    const int cg = (tid & 15) * 16;
    #pragma unroll
    for (int q = 0; q < 4; ++q) {
        float4 g4 = ((const float4*)(gamma + cg))[q];
        float4 b4 = ((const float4*)(beta  + cg))[q];
        gm[4*q+0] = g4.x; gm[4*q+1] = g4.y; gm[4*q+2] = g4.z; gm[4*q+3] = g4.w;
        bt[4*q+0] = b4.x; bt[4*q+1] = b4.y; bt[4*q+2] = b4.z; bt[4*q+3] = b4.w;
    }
    #pragma unroll
    for (int it = 0; it < ROWS / 16; ++it) {
        const int r  = it * 16 + (tid >> 4);
        const int xr = idx[m0 * KNN + r];
        const float4* xp = (const float4*)(x + (size_t)xr * C_IN) + (tid & 15) * 4;
        float vv[16];
        float s = 0.f, sq = 0.f;
        #pragma unroll
        for (int q = 0; q < 4; ++q) {
            float4 v4 = xp[q];
            vv[4*q+0] = v4.x; vv[4*q+1] = v4.y; vv[4*q+2] = v4.z; vv[4*q+3] = v4.w;
        }
        #pragma unroll
        for (int e = 0; e < 16; ++e) { s += vv[e]; sq += vv[e]*vv[e]; }
        #pragma unroll
        for (int o = 1; o < 16; o <<= 1) {
            s  += __shfl_xor(s, o);
            sq += __shfl_xor(sq, o);
        }
        const float mu  = s * (1.0f/256.0f);
        const float var = sq * (1.0f/256.0f) - mu * mu;
        const float rs  = rsqrtf(var + 1e-5f);
        ushort8 c0, c1;
        #pragma unroll
        for (int e = 0; e < 8; ++e) c0[e] = f2h((vv[e]   - mu)*rs*gm[e]   + bt[e]);
        #pragma unroll
        for (int e = 0; e < 8; ++e) c1[e] = f2h((vv[e+8] - mu)*rs*gm[e+8] + bt[e+8]);
        const int cb = (tid & 15) * 32;
        *(ushort8*)(Ab + r*ROWB + cb)      = c0;
        *(ushort8*)(Ab + r*ROWB + cb + 16) = c1;
    }
    __syncthreads();

    // ---- Phase 2: wave = point. A-frags once into named regs, then 32 col-tiles ----
    const int rb   = (wave * 16 + (lane & 15)) * ROWB;   // this wave's point rows
    const int csub = (lane >> 4) << 4;

    const f16x8 af0 = *(const f16x8*)(Ab + rb + 0*64 + csub);
    const f16x8 af1 = *(const f16x8*)(Ab + rb + 1*64 + csub);
    const f16x8 af2 = *(const f16x8*)(Ab + rb + 2*64 + csub);
    const f16x8 af3 = *(const f16x8*)(Ab + rb + 3*64 + csub);
    const f16x8 af4 = *(const f16x8*)(Ab + rb + 4*64 + csub);
    const f16x8 af5 = *(const f16x8*)(Ab + rb + 5*64 + csub);
    const f16x8 af6 = *(const f16x8*)(Ab + rb + 6*64 + csub);
    const f16x8 af7 = *(const f16x8*)(Ab + rb + 7*64 + csub);

    float* orow = out + (size_t)(m0 + wave) * C_OUT;

    #pragma unroll 1
    for (int nt = 0; nt < 32; ++nt) {
        const f16x8* Bp = (const f16x8*)Wp + (size_t)(nt * 8) * 64 + lane;
        f32x4 acc = {0.f, 0.f, 0.f, 0.f};
        // R9-proven inner shape: named per-kk loads interleaved with MFMAs
        const f16x8 b0 = Bp[0*64];  acc = MFMA16(af0, b0, acc);
        const f16x8 b1 = Bp[1*64];  acc = MFMA16(af1, b1, acc);
        const f16x8 b2 = Bp[2*64];  acc = MFMA16(af2, b2, acc);
        const f16x8 b3 = Bp[3*64];  acc = MFMA16(af3, b3, acc);
        const f16x8 b4 = Bp[4*64];  acc = MFMA16(af4, b4, acc);
        const f16x8 b5 = Bp[5*64];  acc = MFMA16(af5, b5, acc);
        const f16x8 b6 = Bp[6*64];  acc = MFMA16(af6, b6, acc);
        const f16x8 b7 = Bp[7*64];  acc = MFMA16(af7, b7, acc);

        float v = fmaxf(fmaxf(acc[0], acc[1]), fmaxf(acc[2], acc[3]));
        v = fmaxf(v, __shfl_xor(v, 16));
        v = fmaxf(v, __shfl_xor(v, 32));
        if (lane < 16) {
            orow[nt*16 + lane] = v + bias[nt*16 + lane];
        }
    }
}

extern "C" void kernel_launch(void* const* d_in, const int* in_sizes, int n_in,
                              void* d_out, int out_size, void* d_ws, size_t ws_size,
                              hipStream_t stream) {
    const float* x     = (const float*)d_in[0];
    const int*   idx   = (const int*)d_in[1];
    const float* gamma = (const float*)d_in[2];
    const float* beta  = (const float*)d_in[3];
    const float* W     = (const float*)d_in[4];
    const float* b     = (const float*)d_in[5];
    float* out = (float*)d_out;
    unsigned short* Wp = (unsigned short*)d_ws;   // 256 KiB scratch

    hipLaunchKernelGGL(pack_w_kernel, dim3((C_IN * C_OUT) / 256), dim3(256), 0, stream, W, Wp);
    hipLaunchKernelGGL(fused_gather_ln_gemm_max, dim3(M_PTS / P_BLK), dim3(NTHREADS), 0, stream,
                       x, idx, gamma, beta, Wp, b, out);
}

// Round 15
// 152.591 us; speedup vs baseline: 1.7968x; 1.7968x over previous
//
#include <hip/hip_runtime.h>

typedef _Float16 f16x8 __attribute__((ext_vector_type(8)));
typedef unsigned short ushort8 __attribute__((ext_vector_type(8)));
typedef float f32x4 __attribute__((ext_vector_type(4)));

#define C_IN     256
#define C_OUT    512
#define M_PTS    25000
#define KNN      16
#define P_BLK    4
#define ROWS     (P_BLK * KNN)   /* 64 */
#define ROWB     528             /* padded row stride in bytes (264 f16), 16B-aligned */
#define NTHREADS 256

#define MFMA16(a, b, c) __builtin_amdgcn_mfma_f32_16x16x32_f16(a, b, c, 0, 0, 0)

__device__ __forceinline__ unsigned short f2h(float f) {
    _Float16 h = (_Float16)f;
    return __builtin_bit_cast(unsigned short, h);
}

// Pack W [C_IN][C_OUT] f32 -> f16 in MFMA B-fragment order (verified):
// Wp[nt*4096 + kk*512 + lane*8 + j] = W[(kk*32 + (lane>>4)*8 + j)*C_OUT + nt*16 + (lane&15)]
__global__ void pack_w_kernel(const float* __restrict__ W, unsigned short* __restrict__ Wp) {
    int t = blockIdx.x * blockDim.x + threadIdx.x;   // 0 .. 131071
    int j    = t & 7;
    int lane = (t >> 3) & 63;
    int kk   = (t >> 9) & 7;
    int nt   = t >> 12;                               // 0..31
    int k = kk * 32 + ((lane >> 4) << 3) + j;
    int n = nt * 16 + (lane & 15);
    Wp[t] = f2h(W[k * C_OUT + n]);
}

// Synthesis of all passing structures (R5/R8/R9/R14):
//  - p-outer loop, small `unroll 1` regions  (R8: best MLP, 153us)
//  - B hoisted ONCE per ntp as 16 NAMED SCALARS (R9-proven residency; kills R8's
//    4x-redundant resunk B stream: 1MB -> 256KB per block)
//  - all MFMA operands named (hazard law: arrays/asm-pins miscompile R6/7/10/13)
// Accumulation order bit-identical to R8 (same kk order per acc).
__global__ __launch_bounds__(NTHREADS, 2)
void fused_gather_ln_gemm_max(const float* __restrict__ x,
                              const int* __restrict__ idx,
                              const float* __restrict__ gamma,
                              const float* __restrict__ beta,
                              const unsigned short* __restrict__ Wp,
                              const float* __restrict__ bias,
                              float* __restrict__ out) {
    __shared__ char Ab[ROWS * ROWB];   // 33 KiB, f16 A-tile, padded rows, NO swizzle

    const int tid  = threadIdx.x;
    const int lane = tid & 63;
    const int wave = tid >> 6;
    const int m0   = blockIdx.x * P_BLK;

    // ---- Phase 1: gather + LayerNorm -> LDS (f16), VERBATIM from passing rounds ----
    float gm[16], bt[16];
    const int cg = (tid & 15) * 16;
    #pragma unroll
    for (int q = 0; q < 4; ++q) {
        float4 g4 = ((const float4*)(gamma + cg))[q];
        float4 b4 = ((const float4*)(beta  + cg))[q];
        gm[4*q+0] = g4.x; gm[4*q+1] = g4.y; gm[4*q+2] = g4.z; gm[4*q+3] = g4.w;
        bt[4*q+0] = b4.x; bt[4*q+1] = b4.y; bt[4*q+2] = b4.z; bt[4*q+3] = b4.w;
    }
    #pragma unroll
    for (int it = 0; it < ROWS / 16; ++it) {
        const int r  = it * 16 + (tid >> 4);
        const int xr = idx[m0 * KNN + r];
        const float4* xp = (const float4*)(x + (size_t)xr * C_IN) + (tid & 15) * 4;
        float vv[16];
        float s = 0.f, sq = 0.f;
        #pragma unroll
        for (int q = 0; q < 4; ++q) {
            float4 v4 = xp[q];
            vv[4*q+0] = v4.x; vv[4*q+1] = v4.y; vv[4*q+2] = v4.z; vv[4*q+3] = v4.w;
        }
        #pragma unroll
        for (int e = 0; e < 16; ++e) { s += vv[e]; sq += vv[e]*vv[e]; }
        #pragma unroll
        for (int o = 1; o < 16; o <<= 1) {
            s  += __shfl_xor(s, o);
            sq += __shfl_xor(sq, o);
        }
        const float mu  = s * (1.0f/256.0f);
        const float var = sq * (1.0f/256.0f) - mu * mu;
        const float rs  = rsqrtf(var + 1e-5f);
        ushort8 c0, c1;
        #pragma unroll
        for (int e = 0; e < 8; ++e) c0[e] = f2h((vv[e]   - mu)*rs*gm[e]   + bt[e]);
        #pragma unroll
        for (int e = 0; e < 8; ++e) c1[e] = f2h((vv[e+8] - mu)*rs*gm[e+8] + bt[e+8]);
        const int cb = (tid & 15) * 32;
        *(ushort8*)(Ab + r*ROWB + cb)      = c0;
        *(ushort8*)(Ab + r*ROWB + cb + 16) = c1;
    }
    __syncthreads();

    // ---- Phase 2: p-outer MFMA GEMM + fused max, B hoisted as named scalars ----
    const int csub = (lane >> 4) << 4;

    #pragma unroll 1
    for (int ntp = 0; ntp < 4; ++ntp) {
        const int nt0 = wave * 8 + ntp * 2;
        const int nt1 = nt0 + 1;
        const f16x8* Bp0 = (const f16x8*)Wp + (size_t)(nt0 * 8) * 64 + lane;
        const f16x8* Bp1 = (const f16x8*)Wp + (size_t)(nt1 * 8) * 64 + lane;

        // 16-deep named-scalar B load burst; stays resident across the p-loop
        const f16x8 B00 = Bp0[0*64], B01 = Bp0[1*64], B02 = Bp0[2*64], B03 = Bp0[3*64];
        const f16x8 B04 = Bp0[4*64], B05 = Bp0[5*64], B06 = Bp0[6*64], B07 = Bp0[7*64];
        const f16x8 B10 = Bp1[0*64], B11 = Bp1[1*64], B12 = Bp1[2*64], B13 = Bp1[3*64];
        const f16x8 B14 = Bp1[4*64], B15 = Bp1[5*64], B16 = Bp1[6*64], B17 = Bp1[7*64];

        const float bias0 = bias[nt0*16 + (lane & 15)];
        const float bias1 = bias[nt1*16 + (lane & 15)];

        #pragma unroll 1
        for (int p = 0; p < P_BLK; ++p) {
            const int rowbase = (p*16 + (lane & 15)) * ROWB;
            const f16x8 fa0 = *(const f16x8*)(Ab + rowbase + 0*64 + csub);
            const f16x8 fa1 = *(const f16x8*)(Ab + rowbase + 1*64 + csub);
            const f16x8 fa2 = *(const f16x8*)(Ab + rowbase + 2*64 + csub);
            const f16x8 fa3 = *(const f16x8*)(Ab + rowbase + 3*64 + csub);
            const f16x8 fa4 = *(const f16x8*)(Ab + rowbase + 4*64 + csub);
            const f16x8 fa5 = *(const f16x8*)(Ab + rowbase + 5*64 + csub);
            const f16x8 fa6 = *(const f16x8*)(Ab + rowbase + 6*64 + csub);
            const f16x8 fa7 = *(const f16x8*)(Ab + rowbase + 7*64 + csub);

            f32x4 acc0 = {0.f,0.f,0.f,0.f}, acc1 = {0.f,0.f,0.f,0.f};
            acc0 = MFMA16(fa0, B00, acc0);  acc1 = MFMA16(fa0, B10, acc1);
            acc0 = MFMA16(fa1, B01, acc0);  acc1 = MFMA16(fa1, B11, acc1);
            acc0 = MFMA16(fa2, B02, acc0);  acc1 = MFMA16(fa2, B12, acc1);
            acc0 = MFMA16(fa3, B03, acc0);  acc1 = MFMA16(fa3, B13, acc1);
            acc0 = MFMA16(fa4, B04, acc0);  acc1 = MFMA16(fa4, B14, acc1);
            acc0 = MFMA16(fa5, B05, acc0);  acc1 = MFMA16(fa5, B15, acc1);
            acc0 = MFMA16(fa6, B06, acc0);  acc1 = MFMA16(fa6, B16, acc1);
            acc0 = MFMA16(fa7, B07, acc0);  acc1 = MFMA16(fa7, B17, acc1);

            float v0 = fmaxf(fmaxf(acc0[0], acc0[1]), fmaxf(acc0[2], acc0[3]));
            float v1 = fmaxf(fmaxf(acc1[0], acc1[1]), fmaxf(acc1[2], acc1[3]));
            v0 = fmaxf(v0, __shfl_xor(v0, 16));
            v0 = fmaxf(v0, __shfl_xor(v0, 32));
            v1 = fmaxf(v1, __shfl_xor(v1, 16));
            v1 = fmaxf(v1, __shfl_xor(v1, 32));
            if (lane < 16) {
                out[(size_t)(m0 + p) * C_OUT + nt0*16 + lane] = v0 + bias0;
                out[(size_t)(m0 + p) * C_OUT + nt1*16 + lane] = v1 + bias1;
            }
        }
    }
}

extern "C" void kernel_launch(void* const* d_in, const int* in_sizes, int n_in,
                              void* d_out, int out_size, void* d_ws, size_t ws_size,
                              hipStream_t stream) {
    const float* x     = (const float*)d_in[0];
    const int*   idx   = (const int*)d_in[1];
    const float* gamma = (const float*)d_in[2];
    const float* beta  = (const float*)d_in[3];
    const float* W     = (const float*)d_in[4];
    const float* b     = (const float*)d_in[5];
    float* out = (float*)d_out;
    unsigned short* Wp = (unsigned short*)d_ws;   // 256 KiB scratch

    hipLaunchKernelGGL(pack_w_kernel, dim3((C_IN * C_OUT) / 256), dim3(256), 0, stream, W, Wp);
    hipLaunchKernelGGL(fused_gather_ln_gemm_max, dim3(M_PTS / P_BLK), dim3(NTHREADS), 0, stream,
                       x, idx, gamma, beta, Wp, b, out);
}

// Round 17
// 152.371 us; speedup vs baseline: 1.7994x; 1.0014x over previous
//
#include <hip/hip_runtime.h>

typedef _Float16 f16x8 __attribute__((ext_vector_type(8)));
typedef unsigned short ushort8 __attribute__((ext_vector_type(8)));
typedef float f32x4 __attribute__((ext_vector_type(4)));

#define C_IN     256
#define C_OUT    512
#define M_PTS    25000
#define KNN      16
#define P_BLK    4
#define ROWS     (P_BLK * KNN)   /* 64 */
#define ROWB     528             /* padded row stride in bytes (264 f16), 16B-aligned */
#define NTHREADS 256

#define MFMA16(a, b, c) __builtin_amdgcn_mfma_f32_16x16x32_f16(a, b, c, 0, 0, 0)

__device__ __forceinline__ unsigned short f2h(float f) {
    _Float16 h = (_Float16)f;
    return __builtin_bit_cast(unsigned short, h);
}

// Pack W [C_IN][C_OUT] f32 -> f16 in MFMA B-fragment order (verified):
// Wp[nt*4096 + kk*512 + lane*8 + j] = W[(kk*32 + (lane>>4)*8 + j)*C_OUT + nt*16 + (lane&15)]
__global__ void pack_w_kernel(const float* __restrict__ W, unsigned short* __restrict__ Wp) {
    int t = blockIdx.x * blockDim.x + threadIdx.x;   // 0 .. 131071
    int j    = t & 7;
    int lane = (t >> 3) & 63;
    int kk   = (t >> 9) & 7;
    int nt   = t >> 12;                               // 0..31
    int k = kk * 32 + ((lane >> 4) << 3) + j;
    int n = nt * 16 + (lane & 15);
    Wp[t] = f2h(W[k * C_OUT + n]);
}

// HAZARD LAW (final, R6/R7/R10/R13/R16): ANY form holding ~16 f16x8 MFMA input
// operands live across MFMA regions miscompiles (array, asm-pin, or named+CSE).
// Safe forms keep <=4 input operands live (R5/R8/R9/R11/R12/R14). So B residency
// in registers is unattainable; instead attack R9's LATENCY problem:
//   R9 = traffic-optimal but 132 total regs (100 arch + 32 acc) > 128 unified
//   boundary -> 2 waves/SIMD (21% occ) -> L2 latency exposed -> 188us.
// This kernel: R9 inner shape at HALF pressure — 2-point chunks, per kk:
// 2 named B + 2 named A + 4 MFMA, 4 acc chains (16 f32). Est regs ~90 < 128
// -> 4 waves/SIMD, 4 blocks/CU (LDS 135KB), ~50% occupancy. B resunk per chunk
// -> 3.2GB L2 (half of R8, under the 34.5TB/s ceiling at target runtime).
__global__ __launch_bounds__(NTHREADS, 4)
void fused_gather_ln_gemm_max(const float* __restrict__ x,
                              const int* __restrict__ idx,
                              const float* __restrict__ gamma,
                              const float* __restrict__ beta,
                              const unsigned short* __restrict__ Wp,
                              const float* __restrict__ bias,
                              float* __restrict__ out) {
    __shared__ char Ab[ROWS * ROWB];   // 33 KiB, f16 A-tile, padded rows, NO swizzle

    const int tid  = threadIdx.x;
    const int lane = tid & 63;
    const int wave = tid >> 6;
    const int m0   = blockIdx.x * P_BLK;

    // ---- Phase 1: gather + LayerNorm -> LDS (f16), VERBATIM from passing rounds ----
    float gm[16], bt[16];
    const int cg = (tid & 15) * 16;
    #pragma unroll
    for (int q = 0; q < 4; ++q) {
        float4 g4 = ((const float4*)(gamma + cg))[q];
        float4 b4 = ((const float4*)(beta  + cg))[q];
        gm[4*q+0] = g4.x; gm[4*q+1] = g4.y; gm[4*q+2] = g4.z; gm[4*q+3] = g4.w;
        bt[4*q+0] = b4.x; bt[4*q+1] = b4.y; bt[4*q+2] = b4.z; bt[4*q+3] = b4.w;
    }
    #pragma unroll
    for (int it = 0; it < ROWS / 16; ++it) {
        const int r  = it * 16 + (tid >> 4);
        const int xr = idx[m0 * KNN + r];
        const float4* xp = (const float4*)(x + (size_t)xr * C_IN) + (tid & 15) * 4;
        float vv[16];
        float s = 0.f, sq = 0.f;
        #pragma unroll
        for (int q = 0; q < 4; ++q) {
            float4 v4 = xp[q];
            vv[4*q+0] = v4.x; vv[4*q+1] = v4.y; vv[4*q+2] = v4.z; vv[4*q+3] = v4.w;
        }
        #pragma unroll
        for (int e = 0; e < 16; ++e) { s += vv[e]; sq += vv[e]*vv[e]; }
        #pragma unroll
        for (int o = 1; o < 16; o <<= 1) {
            s  += __shfl_xor(s, o);
            sq += __shfl_xor(sq, o);
        }
        const float mu  = s * (1.0f/256.0f);
        const float var = sq * (1.0f/256.0f) - mu * mu;
        const float rs  = rsqrtf(var + 1e-5f);
        ushort8 c0, c1;
        #pragma unroll
        for (int e = 0; e < 8; ++e) c0[e] = f2h((vv[e]   - mu)*rs*gm[e]   + bt[e]);
        #pragma unroll
        for (int e = 0; e < 8; ++e) c1[e] = f2h((vv[e+8] - mu)*rs*gm[e+8] + bt[e+8]);
        const int cb = (tid & 15) * 32;
        *(ushort8*)(Ab + r*ROWB + cb)      = c0;
        *(ushort8*)(Ab + r*ROWB + cb + 16) = c1;
    }
    __syncthreads();

    // ---- Phase 2: kk-outer, 2-point chunks (low pressure: 2B + 2A + 4 acc live) ----
    const int csub = (lane >> 4) << 4;
    const int rlo  = lane & 15;

    #pragma unroll 1
    for (int ntp = 0; ntp < 4; ++ntp) {
        const int nt0 = wave * 8 + ntp * 2;
        const int nt1 = nt0 + 1;
        const f16x8* Bp0 = (const f16x8*)Wp + (size_t)(nt0 * 8) * 64 + lane;
        const f16x8* Bp1 = (const f16x8*)Wp + (size_t)(nt1 * 8) * 64 + lane;
        const float bias0 = bias[nt0*16 + rlo];
        const float bias1 = bias[nt1*16 + rlo];

        #pragma unroll 1
        for (int pc = 0; pc < P_BLK; pc += 2) {
            const int rbA = ((pc+0)*16 + rlo) * ROWB;
            const int rbB = ((pc+1)*16 + rlo) * ROWB;
            f32x4 a00 = {0.f,0.f,0.f,0.f}, a01 = {0.f,0.f,0.f,0.f};
            f32x4 a10 = {0.f,0.f,0.f,0.f}, a11 = {0.f,0.f,0.f,0.f};
            #pragma unroll
            for (int kk = 0; kk < 8; ++kk) {
                const f16x8 b0 = Bp0[kk*64];
                const f16x8 b1 = Bp1[kk*64];
                const int co = kk*64 + csub;
                const f16x8 fa0 = *(const f16x8*)(Ab + rbA + co);
                const f16x8 fa1 = *(const f16x8*)(Ab + rbB + co);
                a00 = MFMA16(fa0, b0, a00);  a01 = MFMA16(fa0, b1, a01);
                a10 = MFMA16(fa1, b0, a10);  a11 = MFMA16(fa1, b1, a11);
            }
            float v0 = fmaxf(fmaxf(a00[0], a00[1]), fmaxf(a00[2], a00[3]));
            float v1 = fmaxf(fmaxf(a01[0], a01[1]), fmaxf(a01[2], a01[3]));
            float v2 = fmaxf(fmaxf(a10[0], a10[1]), fmaxf(a10[2], a10[3]));
            float v3 = fmaxf(fmaxf(a11[0], a11[1]), fmaxf(a11[2], a11[3]));
            v0 = fmaxf(v0, __shfl_xor(v0, 16)); v0 = fmaxf(v0, __shfl_xor(v0, 32));
            v1 = fmaxf(v1, __shfl_xor(v1, 16)); v1 = fmaxf(v1, __shfl_xor(v1, 32));
            v2 = fmaxf(v2, __shfl_xor(v2, 16)); v2 = fmaxf(v2, __shfl_xor(v2, 32));
            v3 = fmaxf(v3, __shfl_xor(v3, 16)); v3 = fmaxf(v3, __shfl_xor(v3, 32));
            if (lane < 16) {
                out[(size_t)(m0 + pc + 0) * C_OUT + nt0*16 + lane] = v0 + bias0;
                out[(size_t)(m0 + pc + 0) * C_OUT + nt1*16 + lane] = v1 + bias1;
                out[(size_t)(m0 + pc + 1) * C_OUT + nt0*16 + lane] = v2 + bias0;
                out[(size_t)(m0 + pc + 1) * C_OUT + nt1*16 + lane] = v3 + bias1;
            }
        }
    }
}

extern "C" void kernel_launch(void* const* d_in, const int* in_sizes, int n_in,
                              void* d_out, int out_size, void* d_ws, size_t ws_size,
                              hipStream_t stream) {
    const float* x     = (const float*)d_in[0];
    const int*   idx   = (const int*)d_in[1];
    const float* gamma = (const float*)d_in[2];
    const float* beta  = (const float*)d_in[3];
    const float* W     = (const float*)d_in[4];
    const float* b     = (const float*)d_in[5];
    float* out = (float*)d_out;
    unsigned short* Wp = (unsigned short*)d_ws;   // 256 KiB scratch

    hipLaunchKernelGGL(pack_w_kernel, dim3((C_IN * C_OUT) / 256), dim3(256), 0, stream, W, Wp);
    hipLaunchKernelGGL(fused_gather_ln_gemm_max, dim3(M_PTS / P_BLK), dim3(NTHREADS), 0, stream,
                       x, idx, gamma, beta, Wp, b, out);
}